// Round 13
// baseline (352.843 us; speedup 1.0000x reference)
//
#include <hip/hip_runtime.h>

#define EPSF 1e-8f

constexpr int NB = 64;   // batch
constexpr int NO = 64;   // out capsules
constexpr int NI = 1152; // in capsules
constexpr int ND = 16;   // pose dims

constexpr int RSTRIDE = 260;            // 256 floats + 4 pad (16B-aligned rows)
constexpr int BUFSZ   = 64 * RSTRIDE;   // one W-tile: 64 o-rows (66,560 B)

typedef float v2f __attribute__((ext_vector_type(2)));
typedef float v4f __attribute__((ext_vector_type(4)));

// Accumulated measured laws (R0-R12):
//  - HW arch-VGPR pool ~256/SIMD; waves/SIMD = floor(256/VGPR). 128-VGPR
//    waves -> 2/SIMD -> 8 waves/CU -> ~128-131 us/heavy-pass regardless of
//    block organization (1x8w == 2x4w).
//  - launch_bounds 2nd arg honored at 512-thr ((512,2)->128, (512,4)->64+
//    spill) but IGNORED at 256-thr (R7:144, R11:108).
//  - 64-VGPR spills catastrophically (R1). 1024-thr fails launch (R3/R4).
//  - grid.sync ~110 us each (R9) -- never fuse.
//  - pair-layout LDS tile: unmodeled 36.6M bank conflicts (R11) -- full-row
//    260-stride only. fp32 V-materialization needs 337 MB ws (n/a, R10).
// This round: e-pass register-pressure relief (raw moments + streamed madj/
// i2v + V-recompute) to expose ds_read ILP within the 128-reg cap.

// fp32 row loader ------------------------------------------------------------
__device__ __forceinline__ void loadrow16f(const float* __restrict__ base,
                                           size_t elem, float* f){
  const float4* p = (const float4*)(base + elem);
  float4 x0=p[0], x1=p[1], x2=p[2], x3=p[3];
  f[0]=x0.x; f[1]=x0.y; f[2]=x0.z; f[3]=x0.w;
  f[4]=x1.x; f[5]=x1.y; f[6]=x1.z; f[7]=x1.w;
  f[8]=x2.x; f[9]=x2.y; f[10]=x2.z; f[11]=x2.w;
  f[12]=x3.x; f[13]=x3.y; f[14]=x3.z; f[15]=x3.w;
}

// async global->LDS, 16 B per lane; lds dst is wave-uniform base + lane*16
__device__ __forceinline__ void gl_lds16(const float* g, float* l){
  __builtin_amdgcn_global_load_lds(
      (const __attribute__((address_space(1))) unsigned int*)g,
      (__attribute__((address_space(3))) unsigned int*)l,
      16, 0, 0);
}

// ---------------- m-pass heavy kernel (R8/R12-proven slim body) -------------
__global__ __launch_bounds__(256, 2) void k_mpass(
    const float* __restrict__ u, const float* __restrict__ W,
    float* __restrict__ S1p, float* __restrict__ S2p, float* __restrict__ Wsp,
    const int CH)
{
  const int CI = NI / CH;
  const int bid = blockIdx.x;
  const int bg = bid / CH, c = bid % CH;
  const int t = threadIdx.x, lane = t & 63, w = t >> 6;
  const int b0 = bg*8 + 2*w, b1 = b0 + 1;
  const int i0 = c*CI;

  __shared__ float buf[BUFSZ];   // 66,560 B -> 2 blocks/CU

  v2f S1[16], S2[16]; v2f wsum = {0.f, 0.f};
  #pragma unroll
  for (int e=0;e<16;++e){ S1[e]=v2f{0.f,0.f}; S2[e]=v2f{0.f,0.f}; }

  const float* row = &buf[lane*RSTRIDE];

  for (int ii=0; ii<CI; ++ii){
    const int i = i0 + ii;
    __syncthreads();               // prior column's buf reads complete
    {
      const float* g = W + (size_t)i*256 + (size_t)(w*16)*NI*256
                         + (size_t)lane*4;
      float* l = buf + (w*16)*RSTRIDE;
      #pragma unroll 1
      for (int r=0;r<16;++r){
        gl_lds16(g, l);
        g += (size_t)NI*256;
        l += RSTRIDE;
      }
    }

    v2f u01[16];
    {
      const float4* pa = (const float4*)(u + ((size_t)b0*NI + i)*ND);
      const float4* pb = (const float4*)(u + ((size_t)b1*NI + i)*ND);
      #pragma unroll
      for (int q=0;q<4;++q){
        float4 xa = pa[q], xb = pb[q];
        u01[q*4+0] = v2f{xa.x, xb.x};
        u01[q*4+1] = v2f{xa.y, xb.y};
        u01[q*4+2] = v2f{xa.z, xb.z};
        u01[q*4+3] = v2f{xa.w, xb.w};
      }
    }
    v2f ss = {0.f, 0.f};
    #pragma unroll
    for (int d=0;d<16;++d){ v2f x = u01[d] + EPSF; ss += x*x; }
    const v2f av = {sqrtf(ss.x), sqrtf(ss.y)};

    __syncthreads();               // stage DMA drained

    #pragma unroll
    for (int e=0;e<16;++e){
      v2f Ve = {0.f, 0.f};
      #pragma unroll
      for (int dq=0; dq<4; ++dq){
        const float4 wv = *(const float4*)(row + e*16 + dq*4);
        const int d = dq*4;
        Ve += wv.x*u01[d+0];
        Ve += wv.y*u01[d+1];
        Ve += wv.z*u01[d+2];
        Ve += wv.w*u01[d+3];
      }
      v2f tv = av*Ve;
      S1[e] += tv;
      S2[e] += tv*Ve;
    }
    wsum += av;
  }

  const size_t ba = (((size_t)b0*CH + c)*NO + lane);
  const size_t bb = (((size_t)b1*CH + c)*NO + lane);
  #pragma unroll
  for (int e=0;e<16;++e){
    S1p[ba*ND+e]=S1[e].x; S2p[ba*ND+e]=S2[e].x;
    S1p[bb*ND+e]=S1[e].y; S2p[bb*ND+e]=S2[e].y;
  }
  Wsp[ba] = wsum.x; Wsp[bb] = wsum.y;   // = per-slice sum of a_i
}

// ---------------- e-pass: low-register-pressure variant ---------------------
// R0 geometry (NW=8, 512-thr, 133 KB dbuf, cap 128) but held state cut to
// S1/S2 + u01 (~100 regs): RAW moments (bias restored in k_final<true>),
// madj/i2v streamed per column (L2-resident; madj = mean-(bias+EPS) from
// k_mred<true>, so raw-V distance == full-V distance exactly -- numerics
// chain validated on HW in R11), V recomputed for the S-accumulate (pass 2)
// instead of held across the softmax. Compiler fence between passes stops
// CSE from re-caching V[16].
template<int NW>
__global__ __launch_bounds__(NW*64, 2) void k_epass(
    const float* __restrict__ u, const float* __restrict__ W,
    const float* __restrict__ madj, const float* __restrict__ i2v0,
    const float* __restrict__ c0,
    float* __restrict__ S1p, float* __restrict__ S2p, float* __restrict__ Wsp,
    const int CH)
{
  const int CI = NI / CH;
  constexpr int ROWS = 64 / NW;
  const int bid = blockIdx.x;
  const int bg = bid / CH, c = bid % CH;
  const int t = threadIdx.x, lane = t & 63, w = t >> 6;
  const int b0 = bg*(2*NW) + 2*w, b1 = b0 + 1;
  const int i0 = c*CI;

  __shared__ float buf[2*BUFSZ];   // 133,120 B

  const v2f c01 = {c0[(size_t)b0*NO + lane], c0[(size_t)b1*NO + lane]};
  const float4* ma0 = (const float4*)(madj + ((size_t)b0*NO + lane)*ND);
  const float4* ma1 = (const float4*)(madj + ((size_t)b1*NO + lane)*ND);
  const float4* iva = (const float4*)(i2v0 + ((size_t)b0*NO + lane)*ND);
  const float4* ivb = (const float4*)(i2v0 + ((size_t)b1*NO + lane)*ND);

  v2f S1[16], S2[16]; v2f wsum = {0.f, 0.f};
  #pragma unroll
  for (int e=0;e<16;++e){ S1[e]=v2f{0.f,0.f}; S2[e]=v2f{0.f,0.f}; }

  auto stage = [&](int p, int i){
    const float* gbase = W + (size_t)i*256 + (size_t)lane*4;
    float* lbase = &buf[p*BUFSZ];
    #pragma unroll
    for (int r=0;r<ROWS;++r){
      const int o = w*ROWS + r;
      gl_lds16(gbase + (size_t)o*NI*256, lbase + o*RSTRIDE);
    }
  };

  int p = 0;
  stage(0, i0);

  for (int ii=0; ii<CI; ++ii){
    __syncthreads();
    if (ii+1 < CI) stage(p^1, i0+ii+1);

    const int i = i0 + ii;
    v2f u01[16];
    {
      const float4* pa = (const float4*)(u + ((size_t)b0*NI + i)*ND);
      const float4* pb = (const float4*)(u + ((size_t)b1*NI + i)*ND);
      #pragma unroll
      for (int q=0;q<4;++q){
        float4 xa = pa[q], xb = pb[q];
        u01[q*4+0] = v2f{xa.x, xb.x};
        u01[q*4+1] = v2f{xa.y, xb.y};
        u01[q*4+2] = v2f{xa.z, xb.z};
        u01[q*4+3] = v2f{xa.w, xb.w};
      }
    }
    v2f ss = {0.f, 0.f};
    #pragma unroll
    for (int d=0;d<16;++d){ v2f x = u01[d] + EPSF; ss += x*x; }
    const v2f av = {sqrtf(ss.x), sqrtf(ss.y)};

    const float* row = &buf[p*BUFSZ + lane*RSTRIDE];

    // ---- pass 1: la from inline raw V (V not stored) ----
    v2f la = {0.f, 0.f};
    #pragma unroll
    for (int q=0;q<4;++q){
      const float4 m0 = ma0[q], m1 = ma1[q];
      const float4 w0 = iva[q], w1 = ivb[q];
      #pragma unroll
      for (int k=0;k<4;++k){
        const int e = 4*q + k;
        v2f Ve = {0.f, 0.f};
        #pragma unroll
        for (int dq=0; dq<4; ++dq){
          const float4 wv = *(const float4*)(row + e*16 + dq*4);
          const int d = dq*4;
          Ve += wv.x*u01[d+0];
          Ve += wv.y*u01[d+1];
          Ve += wv.z*u01[d+2];
          Ve += wv.w*u01[d+3];
        }
        const v2f mm = {(&m0.x)[k], (&m1.x)[k]};
        const v2f iw = {(&w0.x)[k], (&w1.x)[k]};
        v2f df = Ve - mm;
        la += df*df*iw;
      }
    }

    asm volatile("" ::: "memory");   // forbid CSE of the V reads into pass 2

    v2f ap = c01 * v2f{__expf(-la.x), __expf(-la.y)};
    float q0 = ap.x, q1 = ap.y;
    #pragma unroll
    for (int off=32; off; off>>=1){
      q0 += __shfl_xor(q0, off);
      q1 += __shfl_xor(q1, off);
    }
    const v2f wg = {ap.x/(q0 + EPSF)*av.x, ap.y/(q1 + EPSF)*av.y};
    wsum += wg;

    // ---- pass 2: recompute raw V, accumulate raw moments ----
    #pragma unroll
    for (int e=0;e<16;++e){
      v2f Ve = {0.f, 0.f};
      #pragma unroll
      for (int dq=0; dq<4; ++dq){
        const float4 wv = *(const float4*)(row + e*16 + dq*4);
        const int d = dq*4;
        Ve += wv.x*u01[d+0];
        Ve += wv.y*u01[d+1];
        Ve += wv.z*u01[d+2];
        Ve += wv.w*u01[d+3];
      }
      v2f tv = wg*Ve;
      S1[e] += tv;
      S2[e] += tv*Ve;
    }
    p ^= 1;
  }

  const size_t ba = (((size_t)b0*CH + c)*NO + lane);
  const size_t bb = (((size_t)b1*CH + c)*NO + lane);
  #pragma unroll
  for (int e=0;e<16;++e){
    S1p[ba*ND+e]=S1[e].x; S2p[ba*ND+e]=S2[e].x;
    S1p[bb*ND+e]=S1[e].y; S2p[bb*ND+e]=S2[e].y;
  }
  Wsp[ba] = wsum.x; Wsp[bb] = wsum.y;
}

// ---------------- e-pass fallback (R0-proven, bias-inclusive) ---------------
__global__ __launch_bounds__(256, 2) void k_heavy4e(
    const float* __restrict__ u, const float* __restrict__ W,
    const float* __restrict__ bias,
    const float* __restrict__ mean0, const float* __restrict__ i2v0,
    const float* __restrict__ c0,
    float* __restrict__ S1p, float* __restrict__ S2p, float* __restrict__ Wsp,
    const int CH)
{
  const int CI = NI / CH;
  const int bid = blockIdx.x;
  const int bg = bid / CH, c = bid % CH;
  const int t = threadIdx.x, lane = t & 63, w = t >> 6;
  const int b0 = bg*8 + 2*w, b1 = b0 + 1;
  const int i0 = c*CI;

  __shared__ float buf[2*BUFSZ];

  float bs[16]; loadrow16f(bias, (size_t)lane*ND, bs);
  v2f mr[16], ir[16]; v2f c01;
  {
    const size_t m0 = ((size_t)b0*NO + lane)*ND;
    const size_t m1 = ((size_t)b1*NO + lane)*ND;
    #pragma unroll
    for (int e=0;e<16;++e){
      mr[e] = v2f{mean0[m0+e], mean0[m1+e]};
      ir[e] = v2f{i2v0[m0+e], i2v0[m1+e]};
    }
    c01 = v2f{c0[(size_t)b0*NO + lane], c0[(size_t)b1*NO + lane]};
  }

  v2f S1[16], S2[16]; v2f wsum = {0.f, 0.f};
  #pragma unroll
  for (int e=0;e<16;++e){ S1[e]=v2f{0.f,0.f}; S2[e]=v2f{0.f,0.f}; }

  auto stage = [&](int p, int i){
    const float* gbase = W + (size_t)i*256 + (size_t)lane*4;
    float* lbase = &buf[p*BUFSZ];
    #pragma unroll
    for (int r=0;r<16;++r){
      const int o = w*16 + r;
      gl_lds16(gbase + (size_t)o*NI*256, lbase + o*RSTRIDE);
    }
  };

  int p = 0;
  stage(0, i0);

  for (int ii=0; ii<CI; ++ii){
    __syncthreads();
    if (ii+1 < CI) stage(p^1, i0+ii+1);

    const int i = i0 + ii;
    v2f u01[16];
    {
      const float4* pa = (const float4*)(u + ((size_t)b0*NI + i)*ND);
      const float4* pb = (const float4*)(u + ((size_t)b1*NI + i)*ND);
      #pragma unroll
      for (int q=0;q<4;++q){
        float4 xa = pa[q], xb = pb[q];
        u01[q*4+0] = v2f{xa.x, xb.x};
        u01[q*4+1] = v2f{xa.y, xb.y};
        u01[q*4+2] = v2f{xa.z, xb.z};
        u01[q*4+3] = v2f{xa.w, xb.w};
      }
    }
    v2f ss = {0.f, 0.f};
    #pragma unroll
    for (int d=0;d<16;++d){ v2f x = u01[d] + EPSF; ss += x*x; }
    const v2f av = {sqrtf(ss.x), sqrtf(ss.y)};

    v2f V[16];
    #pragma unroll
    for (int e=0;e<16;++e){ float bq = bs[e] + EPSF; V[e] = v2f{bq, bq}; }
    const float* row = &buf[p*BUFSZ + lane*RSTRIDE];
    #pragma unroll
    for (int e=0;e<16;++e){
      #pragma unroll
      for (int dq=0; dq<4; ++dq){
        const float4 wv = *(const float4*)(row + e*16 + dq*4);
        const int d = dq*4;
        V[e] += wv.x*u01[d+0];
        V[e] += wv.y*u01[d+1];
        V[e] += wv.z*u01[d+2];
        V[e] += wv.w*u01[d+3];
      }
    }

    v2f la = {0.f, 0.f};
    #pragma unroll
    for (int e=0;e<16;++e){ v2f df = V[e]-mr[e]; la += df*df*ir[e]; }
    v2f ap = c01 * v2f{__expf(-la.x), __expf(-la.y)};
    float q0 = ap.x, q1 = ap.y;
    #pragma unroll
    for (int off=32; off; off>>=1){
      q0 += __shfl_xor(q0, off);
      q1 += __shfl_xor(q1, off);
    }
    v2f wg = v2f{ap.x/(q0 + EPSF)*av.x, ap.y/(q1 + EPSF)*av.y};
    wsum += wg;
    #pragma unroll
    for (int e=0;e<16;++e){
      v2f tv = wg*V[e]; S1[e]+=tv; S2[e]+=tv*V[e];
    }
    p ^= 1;
  }

  const size_t ba = (((size_t)b0*CH + c)*NO + lane);
  const size_t bb = (((size_t)b1*CH + c)*NO + lane);
  #pragma unroll
  for (int e=0;e<16;++e){
    S1p[ba*ND+e]=S1[e].x; S2p[ba*ND+e]=S2[e].x;
    S1p[bb*ND+e]=S1[e].y; S2p[bb*ND+e]=S2[e].y;
  }
  Wsp[ba] = wsum.x; Wsp[bb] = wsum.y;
}

// ---------------- reduce m-step partials -> mean0,i2v0,c0 -------------------
// m-pass partials are always RAW -> restore bias exactly. MADJ selects what
// mean0 receives: madj = mean-(bias+EPS) (for k_epass) or plain mean (for
// the bias-inclusive fallback e-pass).
template<bool MADJ>
__global__ __launch_bounds__(64) void k_mred(
    const float* __restrict__ beta_a, const float* __restrict__ beta_u,
    const float* __restrict__ bias,
    const float* __restrict__ S1p, const float* __restrict__ S2p,
    const float* __restrict__ Wsp, const int CH,
    float* __restrict__ mean0, float* __restrict__ i2v0, float* __restrict__ c0)
{
  const int bo = blockIdx.x;
  const int b = bo >> 6, o = bo & 63;
  const int t = threadIdx.x;
  const int q = t & 3, cg = t >> 2;

  v4f s1 = {0.f,0.f,0.f,0.f}, s2 = {0.f,0.f,0.f,0.f};
  for (int c = cg; c < CH; c += 16){
    const size_t base = ((((size_t)b*CH)+c)*NO + o)*ND + 4*q;
    s1 += *(const v4f*)(S1p + base);
    s2 += *(const v4f*)(S2p + base);
  }
  #pragma unroll
  for (int off=4; off<64; off<<=1){
    #pragma unroll
    for (int k=0;k<4;++k){
      s1[k] += __shfl_xor(s1[k], off);
      s2[k] += __shfl_xor(s2[k], off);
    }
  }
  float wv = 0.f;
  for (int c = t; c < CH; c += 64)
    wv += Wsp[(((size_t)b*CH)+c)*NO + o];
  #pragma unroll
  for (int off=1; off<64; off<<=1) wv += __shfl_xor(wv, off);

  v4f Bq = *(const v4f*)(bias + (size_t)o*ND + 4*q);
  Bq += EPSF;
  // bias restoration (exact algebra; order matters: s2 uses raw s1)
  s2 += 2.f*Bq*s1 + Bq*Bq*wv;
  s1 += Bq*wv;

  const float rrsum = wv * (1.f/64.f);
  const float inv = 1.f/(rrsum + EPSF);
  const float bu = beta_u[o];
  v4f T1 = s1*(1.f/64.f), T2 = s2*(1.f/64.f);
  v4f m   = T1*inv;
  v4f var = (T2 - 2.f*m*T1 + m*m*rrsum)*inv + 1e-4f;
  v4f iv;
  float ctp = 0.f, prp = 1.f;
  #pragma unroll
  for (int k=0;k<4;++k){
    iv[k] = 1.f/(2.f*var[k] + EPSF);
    ctp += bu + __logf(var[k]);
    prp *= var[k];
  }
  ctp += __shfl_xor(ctp, 1); ctp += __shfl_xor(ctp, 2);
  prp *= __shfl_xor(prp, 1); prp *= __shfl_xor(prp, 2);

  const size_t mbase = ((size_t)b*NO + o)*ND;
  if (cg == 0){
    v4f mout = MADJ ? (m - Bq) : m;
    *(v4f*)(mean0 + mbase + 4*q) = mout;
    *(v4f*)(i2v0  + mbase + 4*q) = iv;
  }
  if (t == 0){
    float cost = ctp * rrsum;
    float x  = 5.0e-4f*(beta_a[o] - cost);   // inv_temp iter0 = 0.01*(1-0.95)
    float aj = 1.f/(1.f + __expf(-x));
    float p1 = sqrtf(6.2831853071795864f*prp + EPSF);
    c0[(size_t)b*NO + o] = aj/(p1 + EPSF);
  }
}

// ---------------- final reduce; RAW => restore bias into moments ------------
template<bool RAW>
__global__ __launch_bounds__(64) void k_final(
    const float* __restrict__ beta_a, const float* __restrict__ beta_u,
    const float* __restrict__ bias,
    const float* __restrict__ S1p, const float* __restrict__ S2p,
    const float* __restrict__ Wsp, const int CH,
    float* __restrict__ out)
{
  const int bo = blockIdx.x;
  const int b = bo >> 6, o = bo & 63;
  const int t = threadIdx.x;
  const int q = t & 3, cg = t >> 2;

  v4f s1 = {0.f,0.f,0.f,0.f}, s2 = {0.f,0.f,0.f,0.f};
  for (int c = cg; c < CH; c += 16){
    const size_t base = ((((size_t)b*CH)+c)*NO + o)*ND + 4*q;
    s1 += *(const v4f*)(S1p + base);
    s2 += *(const v4f*)(S2p + base);
  }
  #pragma unroll
  for (int off=4; off<64; off<<=1){
    #pragma unroll
    for (int k=0;k<4;++k){
      s1[k] += __shfl_xor(s1[k], off);
      s2[k] += __shfl_xor(s2[k], off);
    }
  }
  float wv = 0.f;
  for (int c = t; c < CH; c += 64)
    wv += Wsp[(((size_t)b*CH)+c)*NO + o];
  #pragma unroll
  for (int off=1; off<64; off<<=1) wv += __shfl_xor(wv, off);

  if (RAW){
    v4f Bq = *(const v4f*)(bias + (size_t)o*ND + 4*q);
    Bq += EPSF;
    s2 += 2.f*Bq*s1 + Bq*Bq*wv;
    s1 += Bq*wv;
  }

  const float Wsum = wv;
  const float inv = 1.f/(Wsum + EPSF);
  const float bu = beta_u[o];
  v4f m   = s1*inv;
  v4f var = (s2 - 2.f*m*s1 + m*m*Wsum)*inv + 1e-4f;
  float ctp = 0.f, nrm = 0.f;
  #pragma unroll
  for (int k=0;k<4;++k){
    ctp += bu + __logf(var[k]);
    float me = m[k] + EPSF;
    nrm += me*me;
  }
  ctp += __shfl_xor(ctp, 1); ctp += __shfl_xor(ctp, 2);
  nrm += __shfl_xor(nrm, 1); nrm += __shfl_xor(nrm, 2);

  const float cost = ctp * Wsum;
  const float x  = 9.75e-4f*(beta_a[o] - cost);  // inv_temp iter1 = 0.01*(1-0.95^2)
  const float aj = 1.f/(1.f + __expf(-x));
  const float scale = aj/(sqrtf(nrm) + EPSF);
  if (cg == 0){
    *(v4f*)(out + (size_t)bo*ND + 4*q) = scale*m;
  }
}

// ---------------- host ------------------------------------------------------
extern "C" void kernel_launch(void* const* d_in, const int* in_sizes, int n_in,
                              void* d_out, int out_size, void* d_ws, size_t ws_size,
                              hipStream_t stream)
{
  const float* u      = (const float*)d_in[0];
  const float* W      = (const float*)d_in[1];
  const float* beta_a = (const float*)d_in[2];
  const float* beta_u = (const float*)d_in[3];
  const float* bias   = (const float*)d_in[4];
  float* ws  = (float*)d_ws;
  float* out = (float*)d_out;

  const size_t base_f = 2u*NB*NO*ND + NB*NO;                  // 135,168 floats
  auto need = [&](int ch){
    return (base_f + 2u*(size_t)NB*ch*NO*ND + (size_t)NB*ch*NO)*4;
  };
  const bool big = (ws_size >= need(64));
  const int CH = big ? 64 : 32;

  float* mean0= ws;
  float* i2v0 = mean0 + (size_t)NB*NO*ND;
  float* c0   = i2v0 + (size_t)NB*NO*ND;
  float* S1p  = c0   + (size_t)NB*NO;
  float* S2p  = S1p  + (size_t)NB*CH*NO*ND;
  float* Wsp  = S2p  + (size_t)NB*CH*NO*ND;

  // m-pass: slim NW=4 single-buffer kernel, raw moments
  k_mpass<<<(NB/8)*CH, 256, 0, stream>>>(u, W, S1p, S2p, Wsp, CH);
  if (big){
    k_mred<true><<<NB*NO, 64, 0, stream>>>(beta_a, beta_u, bias,
                                           S1p, S2p, Wsp, CH,
                                           mean0, i2v0, c0);   // stores madj
    k_epass<8><<<(NB/16)*CH, 512, 0, stream>>>(u, W, mean0, i2v0, c0,
                                               S1p, S2p, Wsp, CH);
    k_final<true><<<NB*NO, 64, 0, stream>>>(beta_a, beta_u, bias,
                                            S1p, S2p, Wsp, CH, out);
  } else {
    k_mred<false><<<NB*NO, 64, 0, stream>>>(beta_a, beta_u, bias,
                                            S1p, S2p, Wsp, CH,
                                            mean0, i2v0, c0);  // plain mean
    k_heavy4e<<<(NB/8)*CH, 256, 0, stream>>>(u, W, bias,
                                             mean0, i2v0, c0,
                                             S1p, S2p, Wsp, CH);
    k_final<false><<<NB*NO, 64, 0, stream>>>(beta_a, beta_u, bias,
                                             S1p, S2p, Wsp, CH, out);
  }
}

// Round 14
// 317.610 us; speedup vs baseline: 1.1109x; 1.1109x over previous
//
#include <hip/hip_runtime.h>

#define EPSF 1e-8f

constexpr int NB = 64;   // batch
constexpr int NO = 64;   // out capsules
constexpr int NI = 1152; // in capsules
constexpr int ND = 16;   // pose dims

constexpr int RSTRIDE = 260;            // 256 floats + 4 pad (16B-aligned rows)
constexpr int BUFSZ   = 64 * RSTRIDE;   // one W-tile: 64 o-rows (66,560 B)

typedef float v2f __attribute__((ext_vector_type(2)));
typedef float v4f __attribute__((ext_vector_type(4)));

// Accumulated measured laws (R0-R13):
//  - HW arch-VGPR pool ~256/SIMD; waves/SIMD = floor(256/VGPR); 128-VGPR ->
//    8 waves/CU -> ~128-131 us/heavy-pass regardless of block organization.
//  - launch_bounds 2nd arg honored at 512-thr, IGNORED at 256-thr.
//  - 64-VGPR spills catastrophically. 1024-thr fails launch. grid.sync
//    ~110 us each -- never fuse. Pair-layout LDS: unmodeled conflicts.
//  - LDS-read issue is FULLY serial in the heavy passes (R13: +512
//    ds_read_b128/col -> +40 us). Don't add LDS traffic.
//  - R13 also showed: VGPR relief (128->112) alone buys nothing.
// This round: champion (R12) + e-pass statement reorder so the u01 waitcnt
// no longer drains the just-issued next-tile DMA (u-load + consume BEFORE
// stage issue) -> true double-buffering of the W DMA.

// fp32 row loader ------------------------------------------------------------
__device__ __forceinline__ void loadrow16f(const float* __restrict__ base,
                                           size_t elem, float* f){
  const float4* p = (const float4*)(base + elem);
  float4 x0=p[0], x1=p[1], x2=p[2], x3=p[3];
  f[0]=x0.x; f[1]=x0.y; f[2]=x0.z; f[3]=x0.w;
  f[4]=x1.x; f[5]=x1.y; f[6]=x1.z; f[7]=x1.w;
  f[8]=x2.x; f[9]=x2.y; f[10]=x2.z; f[11]=x2.w;
  f[12]=x3.x; f[13]=x3.y; f[14]=x3.z; f[15]=x3.w;
}

// async global->LDS, 16 B per lane; lds dst is wave-uniform base + lane*16
__device__ __forceinline__ void gl_lds16(const float* g, float* l){
  __builtin_amdgcn_global_load_lds(
      (const __attribute__((address_space(1))) unsigned int*)g,
      (__attribute__((address_space(3))) unsigned int*)l,
      16, 0, 0);
}

// ---------------- m-pass heavy kernel (R8/R12-proven slim body) -------------
// NW=4 (256-thr), SINGLE 66,560 B tile -> 2 blocks/CU; inter-block overlap.
// Single-buffer structure necessarily drains DMA at the 2nd barrier; its
// overlap comes from the co-resident partner block. Unchanged from champion.
__global__ __launch_bounds__(256, 2) void k_mpass(
    const float* __restrict__ u, const float* __restrict__ W,
    float* __restrict__ S1p, float* __restrict__ S2p, float* __restrict__ Wsp,
    const int CH)
{
  const int CI = NI / CH;
  const int bid = blockIdx.x;
  const int bg = bid / CH, c = bid % CH;
  const int t = threadIdx.x, lane = t & 63, w = t >> 6;
  const int b0 = bg*8 + 2*w, b1 = b0 + 1;
  const int i0 = c*CI;

  __shared__ float buf[BUFSZ];   // 66,560 B -> 2 blocks/CU

  v2f S1[16], S2[16]; v2f wsum = {0.f, 0.f};
  #pragma unroll
  for (int e=0;e<16;++e){ S1[e]=v2f{0.f,0.f}; S2[e]=v2f{0.f,0.f}; }

  const float* row = &buf[lane*RSTRIDE];

  for (int ii=0; ii<CI; ++ii){
    const int i = i0 + ii;
    __syncthreads();               // prior column's buf reads complete
    {
      const float* g = W + (size_t)i*256 + (size_t)(w*16)*NI*256
                         + (size_t)lane*4;
      float* l = buf + (w*16)*RSTRIDE;
      #pragma unroll 1
      for (int r=0;r<16;++r){
        gl_lds16(g, l);
        g += (size_t)NI*256;
        l += RSTRIDE;
      }
    }

    v2f u01[16];
    {
      const float4* pa = (const float4*)(u + ((size_t)b0*NI + i)*ND);
      const float4* pb = (const float4*)(u + ((size_t)b1*NI + i)*ND);
      #pragma unroll
      for (int q=0;q<4;++q){
        float4 xa = pa[q], xb = pb[q];
        u01[q*4+0] = v2f{xa.x, xb.x};
        u01[q*4+1] = v2f{xa.y, xb.y};
        u01[q*4+2] = v2f{xa.z, xb.z};
        u01[q*4+3] = v2f{xa.w, xb.w};
      }
    }
    v2f ss = {0.f, 0.f};
    #pragma unroll
    for (int d=0;d<16;++d){ v2f x = u01[d] + EPSF; ss += x*x; }
    const v2f av = {sqrtf(ss.x), sqrtf(ss.y)};

    __syncthreads();               // stage DMA drained

    #pragma unroll
    for (int e=0;e<16;++e){
      v2f Ve = {0.f, 0.f};
      #pragma unroll
      for (int dq=0; dq<4; ++dq){
        const float4 wv = *(const float4*)(row + e*16 + dq*4);
        const int d = dq*4;
        Ve += wv.x*u01[d+0];
        Ve += wv.y*u01[d+1];
        Ve += wv.z*u01[d+2];
        Ve += wv.w*u01[d+3];
      }
      v2f tv = av*Ve;
      S1[e] += tv;
      S2[e] += tv*Ve;
    }
    wsum += av;
  }

  const size_t ba = (((size_t)b0*CH + c)*NO + lane);
  const size_t bb = (((size_t)b1*CH + c)*NO + lane);
  #pragma unroll
  for (int e=0;e<16;++e){
    S1p[ba*ND+e]=S1[e].x; S2p[ba*ND+e]=S2[e].x;
    S1p[bb*ND+e]=S1[e].y; S2p[bb*ND+e]=S2[e].y;
  }
  Wsp[ba] = wsum.x; Wsp[bb] = wsum.y;   // = per-slice sum of a_i
}

// ---------------- e-pass heavy kernel (champion + DMA-drain fix) ------------
// R0 geometry (NW=8, 512-thr, 133 KB dbuf, cap (512,2)->128 VGPR).
// KEY CHANGE vs R12: per column the order is now
//   sync -> u-load -> consume u01 (ss/av; waits ONLY on u01 because the
//   stage DMAs are not yet issued) -> stage(p^1) -> V-compute (ds_read) ...
// Previously stage was issued before the u01 loads, so the compiler's wait
// before consuming u01 (youngest vmem op => vmcnt(0)) drained the freshly
// issued next-tile DMA every iteration, serializing DMA in front of compute
// (why single-buf m-pass ~127us == "double-buf" e-pass ~130us). Now the DMA
// stays in flight across the whole compute and is drained by the next
// loop-top barrier.
template<int NW, bool ESTEP>
__global__ __launch_bounds__(NW*64, 2) void k_heavy(
    const float* __restrict__ u, const float* __restrict__ W,
    const float* __restrict__ bias,
    const float* __restrict__ mean0, const float* __restrict__ i2v0,
    const float* __restrict__ c0,
    float* __restrict__ S1p, float* __restrict__ S2p, float* __restrict__ Wsp,
    const int CH)
{
  const int CI = NI / CH;
  constexpr int ROWS = 64 / NW;
  const int bid = blockIdx.x;
  const int bg = bid / CH, c = bid % CH;
  const int t = threadIdx.x, lane = t & 63, w = t >> 6;
  const int b0 = bg*(2*NW) + 2*w, b1 = b0 + 1;
  const int i0 = c*CI;

  __shared__ float buf[2*BUFSZ];   // 133,120 B

  float bs[16]; loadrow16f(bias, (size_t)lane*ND, bs);
  v2f mr[16], ir[16]; v2f c01 = {0.f, 0.f};
  if (ESTEP){
    const size_t m0 = ((size_t)b0*NO + lane)*ND;
    const size_t m1 = ((size_t)b1*NO + lane)*ND;
    #pragma unroll
    for (int e=0;e<16;++e){
      mr[e] = v2f{mean0[m0+e], mean0[m1+e]};
      ir[e] = v2f{i2v0[m0+e], i2v0[m1+e]};
    }
    c01 = v2f{c0[(size_t)b0*NO + lane], c0[(size_t)b1*NO + lane]};
  }

  v2f S1[16], S2[16]; v2f wsum = {0.f, 0.f};
  #pragma unroll
  for (int e=0;e<16;++e){ S1[e]=v2f{0.f,0.f}; S2[e]=v2f{0.f,0.f}; }

  auto stage = [&](int p, int i){
    const float* gbase = W + (size_t)i*256 + (size_t)lane*4;
    float* lbase = &buf[p*BUFSZ];
    #pragma unroll
    for (int r=0;r<ROWS;++r){
      const int o = w*ROWS + r;
      gl_lds16(gbase + (size_t)o*NI*256, lbase + o*RSTRIDE);
    }
  };

  int p = 0;
  stage(0, i0);

  for (int ii=0; ii<CI; ++ii){
    __syncthreads();   // drains prev-iter stage => buf[p] ready (vmcnt0+bar)

    const int i = i0 + ii;
    // ---- u loads + consume FIRST (only u01 outstanding -> cheap wait) ----
    v2f u01[16];
    {
      const float4* pa = (const float4*)(u + ((size_t)b0*NI + i)*ND);
      const float4* pb = (const float4*)(u + ((size_t)b1*NI + i)*ND);
      #pragma unroll
      for (int q=0;q<4;++q){
        float4 xa = pa[q], xb = pb[q];
        u01[q*4+0] = v2f{xa.x, xb.x};
        u01[q*4+1] = v2f{xa.y, xb.y};
        u01[q*4+2] = v2f{xa.z, xb.z};
        u01[q*4+3] = v2f{xa.w, xb.w};
      }
    }
    v2f ss = {0.f, 0.f};
    #pragma unroll
    for (int d=0;d<16;++d){ v2f x = u01[d] + EPSF; ss += x*x; }
    const v2f av = {sqrtf(ss.x), sqrtf(ss.y)};

    // ---- NOW issue next-tile DMA: stays in flight across all compute ----
    if (ii+1 < CI) stage(p^1, i0+ii+1);

    v2f V[16];
    #pragma unroll
    for (int e=0;e<16;++e){ float b = bs[e] + EPSF; V[e] = v2f{b, b}; }
    const float* row = &buf[p*BUFSZ + lane*RSTRIDE];
    #pragma unroll
    for (int e=0;e<16;++e){
      #pragma unroll
      for (int dq=0; dq<4; ++dq){
        const float4 wv = *(const float4*)(row + e*16 + dq*4);
        const int d = dq*4;
        V[e] += wv.x*u01[d+0];
        V[e] += wv.y*u01[d+1];
        V[e] += wv.z*u01[d+2];
        V[e] += wv.w*u01[d+3];
      }
    }

    v2f wg;
    if (ESTEP){
      v2f la = {0.f, 0.f};
      #pragma unroll
      for (int e=0;e<16;++e){ v2f df = V[e]-mr[e]; la += df*df*ir[e]; }
      v2f ap = c01 * v2f{__expf(-la.x), __expf(-la.y)};
      float q0 = ap.x, q1 = ap.y;
      #pragma unroll
      for (int off=32; off; off>>=1){
        q0 += __shfl_xor(q0, off);
        q1 += __shfl_xor(q1, off);
      }
      wg = v2f{ap.x/(q0 + EPSF)*av.x, ap.y/(q1 + EPSF)*av.y};
    } else {
      wg = av;
    }
    wsum += wg;
    #pragma unroll
    for (int e=0;e<16;++e){
      v2f tv = wg*V[e]; S1[e]+=tv; S2[e]+=tv*V[e];
    }
    p ^= 1;
  }

  const size_t ba = (((size_t)b0*CH + c)*NO + lane);
  const size_t bb = (((size_t)b1*CH + c)*NO + lane);
  #pragma unroll
  for (int e=0;e<16;++e){
    S1p[ba*ND+e]=S1[e].x; S2p[ba*ND+e]=S2[e].x;
    S1p[bb*ND+e]=S1[e].y; S2p[bb*ND+e]=S2[e].y;
  }
  Wsp[ba] = wsum.x; Wsp[bb] = wsum.y;
}

// ---------------- reduce m-step partials -> mean0,i2v0,c0 -------------------
// Wave-parallel (R5) + exact bias restoration for the raw m-pass partials.
__global__ __launch_bounds__(64) void k_mred(
    const float* __restrict__ beta_a, const float* __restrict__ beta_u,
    const float* __restrict__ bias,
    const float* __restrict__ S1p, const float* __restrict__ S2p,
    const float* __restrict__ Wsp, const int CH,
    float* __restrict__ mean0, float* __restrict__ i2v0, float* __restrict__ c0)
{
  const int bo = blockIdx.x;
  const int b = bo >> 6, o = bo & 63;
  const int t = threadIdx.x;
  const int q = t & 3, cg = t >> 2;

  v4f s1 = {0.f,0.f,0.f,0.f}, s2 = {0.f,0.f,0.f,0.f};
  for (int c = cg; c < CH; c += 16){
    const size_t base = ((((size_t)b*CH)+c)*NO + o)*ND + 4*q;
    s1 += *(const v4f*)(S1p + base);
    s2 += *(const v4f*)(S2p + base);
  }
  #pragma unroll
  for (int off=4; off<64; off<<=1){
    #pragma unroll
    for (int k=0;k<4;++k){
      s1[k] += __shfl_xor(s1[k], off);
      s2[k] += __shfl_xor(s2[k], off);
    }
  }
  float wv = 0.f;
  for (int c = t; c < CH; c += 64)
    wv += Wsp[(((size_t)b*CH)+c)*NO + o];
  #pragma unroll
  for (int off=1; off<64; off<<=1) wv += __shfl_xor(wv, off);

  // bias restoration (exact algebra; order matters: s2 uses raw s1)
  {
    v4f Bq = *(const v4f*)(bias + (size_t)o*ND + 4*q);
    Bq += EPSF;
    s2 += 2.f*Bq*s1 + Bq*Bq*wv;
    s1 += Bq*wv;
  }

  const float rrsum = wv * (1.f/64.f);
  const float inv = 1.f/(rrsum + EPSF);
  const float bu = beta_u[o];
  v4f T1 = s1*(1.f/64.f), T2 = s2*(1.f/64.f);
  v4f m   = T1*inv;
  v4f var = (T2 - 2.f*m*T1 + m*m*rrsum)*inv + 1e-4f;
  v4f iv;
  float ctp = 0.f, prp = 1.f;
  #pragma unroll
  for (int k=0;k<4;++k){
    iv[k] = 1.f/(2.f*var[k] + EPSF);
    ctp += bu + __logf(var[k]);
    prp *= var[k];
  }
  ctp += __shfl_xor(ctp, 1); ctp += __shfl_xor(ctp, 2);
  prp *= __shfl_xor(prp, 1); prp *= __shfl_xor(prp, 2);

  const size_t mbase = ((size_t)b*NO + o)*ND;
  if (cg == 0){
    *(v4f*)(mean0 + mbase + 4*q) = m;
    *(v4f*)(i2v0  + mbase + 4*q) = iv;
  }
  if (t == 0){
    float cost = ctp * rrsum;
    float x  = 5.0e-4f*(beta_a[o] - cost);   // inv_temp iter0 = 0.01*(1-0.95)
    float aj = 1.f/(1.f + __expf(-x));
    float p1 = sqrtf(6.2831853071795864f*prp + EPSF);
    c0[(size_t)b*NO + o] = aj/(p1 + EPSF);
  }
}

// ---------------- final: reduce e-partials (bias-inclusive), write out ------
__global__ __launch_bounds__(64) void k_final(
    const float* __restrict__ beta_a, const float* __restrict__ beta_u,
    const float* __restrict__ S1p, const float* __restrict__ S2p,
    const float* __restrict__ Wsp, const int CH,
    float* __restrict__ out)
{
  const int bo = blockIdx.x;
  const int b = bo >> 6, o = bo & 63;
  const int t = threadIdx.x;
  const int q = t & 3, cg = t >> 2;

  v4f s1 = {0.f,0.f,0.f,0.f}, s2 = {0.f,0.f,0.f,0.f};
  for (int c = cg; c < CH; c += 16){
    const size_t base = ((((size_t)b*CH)+c)*NO + o)*ND + 4*q;
    s1 += *(const v4f*)(S1p + base);
    s2 += *(const v4f*)(S2p + base);
  }
  #pragma unroll
  for (int off=4; off<64; off<<=1){
    #pragma unroll
    for (int k=0;k<4;++k){
      s1[k] += __shfl_xor(s1[k], off);
      s2[k] += __shfl_xor(s2[k], off);
    }
  }
  float wv = 0.f;
  for (int c = t; c < CH; c += 64)
    wv += Wsp[(((size_t)b*CH)+c)*NO + o];
  #pragma unroll
  for (int off=1; off<64; off<<=1) wv += __shfl_xor(wv, off);

  const float Wsum = wv;
  const float inv = 1.f/(Wsum + EPSF);
  const float bu = beta_u[o];
  v4f m   = s1*inv;
  v4f var = (s2 - 2.f*m*s1 + m*m*Wsum)*inv + 1e-4f;
  float ctp = 0.f, nrm = 0.f;
  #pragma unroll
  for (int k=0;k<4;++k){
    ctp += bu + __logf(var[k]);
    float me = m[k] + EPSF;
    nrm += me*me;
  }
  ctp += __shfl_xor(ctp, 1); ctp += __shfl_xor(ctp, 2);
  nrm += __shfl_xor(nrm, 1); nrm += __shfl_xor(nrm, 2);

  const float cost = ctp * Wsum;
  const float x  = 9.75e-4f*(beta_a[o] - cost);  // inv_temp iter1 = 0.01*(1-0.95^2)
  const float aj = 1.f/(1.f + __expf(-x));
  const float scale = aj/(sqrtf(nrm) + EPSF);
  if (cg == 0){
    *(v4f*)(out + (size_t)bo*ND + 4*q) = scale*m;
  }
}

// ---------------- host ------------------------------------------------------
extern "C" void kernel_launch(void* const* d_in, const int* in_sizes, int n_in,
                              void* d_out, int out_size, void* d_ws, size_t ws_size,
                              hipStream_t stream)
{
  const float* u      = (const float*)d_in[0];
  const float* W      = (const float*)d_in[1];
  const float* beta_a = (const float*)d_in[2];
  const float* beta_u = (const float*)d_in[3];
  const float* bias   = (const float*)d_in[4];
  float* ws  = (float*)d_ws;
  float* out = (float*)d_out;

  const size_t base_f = 2u*NB*NO*ND + NB*NO;                  // 135,168 floats
  auto need = [&](int ch){
    return (base_f + 2u*(size_t)NB*ch*NO*ND + (size_t)NB*ch*NO)*4;
  };
  const bool big = (ws_size >= need(64));
  const int CH = big ? 64 : 32;

  float* mean0= ws;
  float* i2v0 = mean0 + (size_t)NB*NO*ND;
  float* c0   = i2v0 + (size_t)NB*NO*ND;
  float* S1p  = c0   + (size_t)NB*NO;
  float* S2p  = S1p  + (size_t)NB*CH*NO*ND;
  float* Wsp  = S2p  + (size_t)NB*CH*NO*ND;

  // m-pass: slim NW=4 single-buffer kernel, 512 blocks -> 2 blocks/CU
  k_mpass<<<(NB/8)*CH, 256, 0, stream>>>(u, W, S1p, S2p, Wsp, CH);
  k_mred<<<NB*NO, 64, 0, stream>>>(beta_a, beta_u, bias, S1p, S2p, Wsp, CH,
                                   mean0, i2v0, c0);
  if (big){
    // e-pass: champion NW=8 dbuf kernel + DMA-drain fix
    k_heavy<8,true><<<(NB/16)*CH, 512, 0, stream>>>(u, W, bias,
                                                    mean0, i2v0, c0,
                                                    S1p, S2p, Wsp, CH);
  } else {
    k_heavy<4,true><<<(NB/8)*CH, 256, 0, stream>>>(u, W, bias,
                                                   mean0, i2v0, c0,
                                                   S1p, S2p, Wsp, CH);
  }
  k_final<<<NB*NO, 64, 0, stream>>>(beta_a, beta_u, S1p, S2p, Wsp, CH, out);
}